// Round 2
// baseline (2559.054 us; speedup 1.0000x reference)
//
#include <hip/hip_runtime.h>
#include <math.h>

// SLIC superpixel segmentation — bit-faithful f32 reimplementation of the JAX ref
// (XLA CPU semantics). Numerics decisions, all aimed at exact label match:
//  - dot(feats, centers) replicates Eigen sgemm: sequential k=0..4 FMA chain
//    (__fmaf_rn), acc from first product.                       [R2 change]
//  - f_sq / c_sq replicate XLA fused mul+reduce: rounded squares, sequential
//    adds, NO fma (fp contract off).
//  - d = (f_sq + c_sq) - 2*dot, three separately-rounded ops.
//  - strict-< argmin (first occurrence, == jnp.argmin).
//  - segment_sum replicated with EXACT ascending-pixel-index sequential adds per
//    cluster, via a stable counting sort (block hist -> prefix -> rank scatter).

#pragma clang fp contract(off)

#define BATCH 8
#define HH 224
#define WW 224
#define HWPIX (HH * WW)        // 50176
#define KSEG 100
#define NBLK (HWPIX / 256)     // 196, exact
#define NITER 10

__device__ __forceinline__ float get_ratio() {
    // ratio = COMPACTNESS / sqrt(H*W/K), computed in double then cast to f32,
    // matching Python float -> jnp weak-type f32 promotion.
    double S = sqrt((double)(HH * WW) / (double)KSEG);
    return (float)(10.0 / S);
}

__global__ void k_init(const float* __restrict__ img, float* __restrict__ centers) {
#pragma clang fp contract(off)
    int b = blockIdx.x;
    int k = threadIdx.x;
    if (k >= KSEG) return;
    int i = k / 10, j = k % 10;
    // cy = floor((i+0.5)*H/g) in double, matching numpy
    int y = (int)floor(((i + 0.5) * (double)HH) / 10.0);
    int x = (int)floor(((j + 0.5) * (double)WW) / 10.0);
    float ratio = get_ratio();
    int n = y * WW + x;
    const float* p = img + ((size_t)b * HWPIX + n) * 3;
    float* c = centers + (b * KSEG + k) * 5;
    c[0] = (float)y * ratio;
    c[1] = (float)x * ratio;
    c[2] = p[0];
    c[3] = p[1];
    c[4] = p[2];
}

// mode 0: write labels + per-block histogram.  mode 1: write final outputs.
__global__ void k_assign(const float* __restrict__ img, const float* __restrict__ centers,
                         int* __restrict__ labels, int* __restrict__ blockHist,
                         float* __restrict__ outLab, float* __restrict__ outMean, int mode) {
#pragma clang fp contract(off)
    __shared__ float c[KSEG * 5];
    __shared__ float csq[KSEG];
    __shared__ int hist[KSEG];
    int b = blockIdx.y, bx = blockIdx.x, tid = threadIdx.x;

    for (int i = tid; i < KSEG * 5; i += 256) c[i] = centers[(size_t)b * KSEG * 5 + i];
    if (tid < KSEG) hist[tid] = 0;
    __syncthreads();
    if (tid < KSEG) {
        const float* ck = c + tid * 5;
        float s = ck[0] * ck[0];       // XLA fused mul+reduce: no fma, seq adds
        s = s + ck[1] * ck[1];
        s = s + ck[2] * ck[2];
        s = s + ck[3] * ck[3];
        s = s + ck[4] * ck[4];
        csq[tid] = s;
    }
    __syncthreads();

    int n = bx * 256 + tid;                 // NBLK*256 == HWPIX exactly, no OOB
    int y = n / WW, x = n - y * WW;
    float ratio = get_ratio();
    float yf = (float)y * ratio, xf = (float)x * ratio;
    const float* p = img + ((size_t)b * HWPIX + n) * 3;
    float r = p[0], g = p[1], bl = p[2];
    float fsq = yf * yf;                    // no fma, seq adds (XLA reduce)
    fsq = fsq + xf * xf;
    fsq = fsq + r * r;
    fsq = fsq + g * g;
    fsq = fsq + bl * bl;

    float dmin = INFINITY;
    int kb = 0;
    for (int k = 0; k < KSEG; ++k) {
        const float* ck = c + k * 5;
        // Eigen sgemm micro-kernel: sequential FMA chain over the contracted dim
        float dot = yf * ck[0];             // == fma(yf, c0, 0)
        dot = __fmaf_rn(xf, ck[1], dot);
        dot = __fmaf_rn(r,  ck[2], dot);
        dot = __fmaf_rn(g,  ck[3], dot);
        dot = __fmaf_rn(bl, ck[4], dot);
        float d = (fsq + csq[k]) - 2.0f * dot;  // three separately-rounded ops
        if (d < dmin) { dmin = d; kb = k; }     // strict < == first-min == jnp.argmin
    }
    labels[(size_t)b * HWPIX + n] = kb;

    if (mode == 0) {
        atomicAdd(&hist[kb], 1);
        __syncthreads();
        if (tid < KSEG) blockHist[((size_t)b * NBLK + bx) * KSEG + tid] = hist[tid];
    } else {
        outLab[(size_t)b * HWPIX + n] = (float)kb;
        float* om = outMean + ((size_t)b * HWPIX + n) * 3;
        om[0] = c[kb * 5 + 2];
        om[1] = c[kb * 5 + 3];
        om[2] = c[kb * 5 + 4];
    }
}

__global__ void k_prefix(const int* __restrict__ blockHist, int* __restrict__ offsets,
                         int* __restrict__ cbase, int* __restrict__ ccount) {
    __shared__ int cnt[KSEG];
    int b = blockIdx.x, k = threadIdx.x;
    int run = 0;
    if (k < KSEG) {
        for (int blk = 0; blk < NBLK; ++blk) run += blockHist[((size_t)b * NBLK + blk) * KSEG + k];
        cnt[k] = run;
    }
    __syncthreads();
    if (k < KSEG) {
        int base = 0;
        for (int j = 0; j < k; ++j) base += cnt[j];
        int off = base;
        for (int blk = 0; blk < NBLK; ++blk) {
            size_t idx = ((size_t)b * NBLK + blk) * KSEG + k;
            int t = blockHist[idx];
            offsets[idx] = off;
            off += t;
        }
        cbase[b * KSEG + k] = base;
        ccount[b * KSEG + k] = run;
    }
}

__global__ void k_scatter(const int* __restrict__ labels, const int* __restrict__ offsets,
                          int* __restrict__ idxlist) {
    __shared__ int lab[256];
    int b = blockIdx.y, bx = blockIdx.x, tid = threadIdx.x;
    int n = bx * 256 + tid;
    int my = labels[(size_t)b * HWPIX + n];
    lab[tid] = my;
    __syncthreads();
    int rank = 0;                            // stable rank within block
    for (int j = 0; j < tid; ++j) rank += (lab[j] == my) ? 1 : 0;
    int pos = offsets[((size_t)b * NBLK + bx) * KSEG + my] + rank;
    idxlist[(size_t)b * HWPIX + pos] = n;
}

__global__ void k_update(const float* __restrict__ img, const int* __restrict__ idxlist,
                         const int* __restrict__ cbase, const int* __restrict__ ccount,
                         float* __restrict__ centers) {
#pragma clang fp contract(off)
    int b = blockIdx.x, k = threadIdx.x;
    if (k >= KSEG) return;
    int base = cbase[b * KSEG + k], cnt = ccount[b * KSEG + k];
    float ratio = get_ratio();
    float s0 = 0.f, s1 = 0.f, s2 = 0.f, s3 = 0.f, s4 = 0.f;
    const int* il = idxlist + (size_t)b * HWPIX;
    const float* ib = img + (size_t)b * HWPIX * 3;
    for (int i = 0; i < cnt; ++i) {          // ascending pixel order == XLA scatter order
        int n = il[base + i];
        int y = n / WW, x = n - y * WW;
        float yf = (float)y * ratio, xf = (float)x * ratio;
        const float* p = ib + (size_t)n * 3;
        s0 = s0 + yf;
        s1 = s1 + xf;
        s2 = s2 + p[0];
        s3 = s3 + p[1];
        s4 = s4 + p[2];
    }
    if (cnt > 0) {                           // where(counts>0, sums/max(counts,1), old)
        float cf = (float)cnt;
        float* c = centers + (b * KSEG + k) * 5;
        c[0] = s0 / cf;
        c[1] = s1 / cf;
        c[2] = s2 / cf;
        c[3] = s3 / cf;
        c[4] = s4 / cf;
    }
}

extern "C" void kernel_launch(void* const* d_in, const int* in_sizes, int n_in,
                              void* d_out, int out_size, void* d_ws, size_t ws_size,
                              hipStream_t stream) {
    const float* img = (const float*)d_in[0];
    float* outLab = (float*)d_out;                         // [8,224,224] labels as f32
    float* outMean = outLab + (size_t)BATCH * HWPIX;       // [8,224,224,3]

    char* ws = (char*)d_ws;
    float* centers = (float*)ws;  ws += (size_t)BATCH * KSEG * 5 * sizeof(float);
    int* labels    = (int*)ws;    ws += (size_t)BATCH * HWPIX * sizeof(int);
    int* blockHist = (int*)ws;    ws += (size_t)BATCH * NBLK * KSEG * sizeof(int);
    int* offsets   = (int*)ws;    ws += (size_t)BATCH * NBLK * KSEG * sizeof(int);
    int* idxlist   = (int*)ws;    ws += (size_t)BATCH * HWPIX * sizeof(int);
    int* cbase     = (int*)ws;    ws += (size_t)BATCH * KSEG * sizeof(int);
    int* ccount    = (int*)ws;    ws += (size_t)BATCH * KSEG * sizeof(int);

    k_init<<<dim3(BATCH), 128, 0, stream>>>(img, centers);
    for (int it = 0; it < NITER; ++it) {
        k_assign<<<dim3(NBLK, BATCH), 256, 0, stream>>>(img, centers, labels, blockHist,
                                                        outLab, outMean, 0);
        k_prefix<<<dim3(BATCH), 128, 0, stream>>>(blockHist, offsets, cbase, ccount);
        k_scatter<<<dim3(NBLK, BATCH), 256, 0, stream>>>(labels, offsets, idxlist);
        k_update<<<dim3(BATCH), 128, 0, stream>>>(img, idxlist, cbase, ccount, centers);
    }
    k_assign<<<dim3(NBLK, BATCH), 256, 0, stream>>>(img, centers, labels, blockHist,
                                                    outLab, outMean, 1);
}